// Round 10
// baseline (134.984 us; speedup 1.0000x reference)
//
#include <hip/hip_runtime.h>

typedef __bf16 v8bf __attribute__((ext_vector_type(8)));
typedef float  v4f  __attribute__((ext_vector_type(4)));

#define D     512
#define NSUP  20
#define NC    64
#define RES   25
#define BB    128
#define LAM   (20.0f/512.0f)
#define KT    32
#define NKT   (D/KT)     // 16
#define CPB   8
#define COLS  160        // CPB*NSUP
#define NFRAG 10         // COLS/16
#define MFRAG 4          // 64 rows / 16

__device__ __forceinline__ ushort bf_hi(float v) {
    uint32_t b = __float_as_uint(v);
    return (ushort)((b + 0x7FFF + ((b >> 16) & 1)) >> 16);   // RNE
}
__device__ __forceinline__ float us2f(ushort u) {
    return __uint_as_float(((uint32_t)u) << 16);
}

// ---- Kernel 1 (fused): Gram + dual register-Cholesky + panel solves --------
//  B = G+lam I = L L^T ; C2 = G+2lam I = R R^T ; W = B^{-1}H ; Htilde = R^T W.
//  Grid (64 classes, 2 halves): each block redoes the (cheap, parallel)
//  Gram+Cholesky in LDS/registers, then solves its 256 columns. No global
//  round-trip for L/R. Block (0,0) also zeroes the k_main tickets.
__global__ __launch_bounds__(256) void k_prep(const float* __restrict__ high,
                                              ushort* __restrict__ Hth,
                                              ushort* __restrict__ Htl,
                                              int* __restrict__ ticket) {
    const int cls  = blockIdx.x;
    const int half = blockIdx.y;
    const int t    = threadIdx.x;
    __shared__ float Hc[NSUP * 516];
    __shared__ float Gs[NSUP * NSUP];
    __shared__ float Ls[400], Rs[400], rL[NSUP];

    if (cls == 0 && half == 0 && t < NC) ticket[t] = 0;   // runs before k_main

    for (int i = t; i < NSUP * (D / 4); i += 256) {
        int r = i >> 7, c4 = (i & 127) << 2;
        *(float4*)&Hc[r * 516 + c4] = *(const float4*)&high[(cls * NSUP + r) * D + c4];
    }
    __syncthreads();

    // Gram — symmetric half only
    for (int e = t; e < NSUP * NSUP; e += 256) {
        int i = e / NSUP, j = e % NSUP;
        if (i <= j) {
            float s = 0.f;
            for (int k = 0; k < D; k += 4) {
                float4 a = *(float4*)&Hc[i * 516 + k];
                float4 b = *(float4*)&Hc[j * 516 + k];
                s += a.x * b.x + a.y * b.y + a.z * b.z + a.w * b.w;
            }
            Gs[i * NSUP + j] = s;
            Gs[j * NSUP + i] = s;
        }
    }
    __syncthreads();

    // dual in-register Cholesky on wave 0 (lanes 0-19: B, 32-51: C2)
    if (t < 64) {
        const int c  = t & 31;
        const int gp = t >> 5;
        const float dlam = gp ? 2.0f * LAM : LAM;
        float m[NSUP];
        if (c < NSUP) {
            #pragma unroll
            for (int i = 0; i < NSUP; ++i) m[i] = Gs[i * NSUP + c];
            #pragma unroll
            for (int i = 0; i < NSUP; ++i) if (i == c) m[i] += dlam;
        }
        #pragma unroll
        for (int k = 0; k < NSUP; ++k) {
            float piv = __shfl(m[k], k, 32);     // M[k][k] from lane k
            float sq  = sqrtf(piv);
            float rsq = 1.0f / sq;
            float lck = m[k] * rsq;              // L[c][k] via symmetry (c>k)
            if (c == k) {
                m[k] = sq;
                #pragma unroll
                for (int i = k + 1; i < NSUP; ++i) m[i] *= rsq;
            }
            #pragma unroll
            for (int i = k + 1; i < NSUP; ++i) {
                float lik = __shfl(m[i], k, 32); // L[i][k] (post-scale)
                if (c > k) m[i] -= lik * lck;
            }
        }
        if (c < NSUP) {
            float* Lout = gp ? Rs : Ls;
            #pragma unroll
            for (int i = 0; i < NSUP; ++i) if (i >= c) Lout[i * NSUP + c] = m[i];
            if (!gp) rL[c] = 1.0f / m[c];
        }
    }
    __syncthreads();

    // panel solves for this block's 256 columns (H read from LDS)
    const int col = half * 256 + t;
    float h[NSUP];
    #pragma unroll
    for (int m = 0; m < NSUP; ++m) h[m] = Hc[m * 516 + col];
    // forward: L z = h   (L reads are wave-uniform broadcasts)
    #pragma unroll
    for (int i = 0; i < NSUP; ++i) {
        float s = h[i];
        #pragma unroll
        for (int m = 0; m < i; ++m) s -= Ls[i * NSUP + m] * h[m];
        h[i] = s * rL[i];
    }
    // backward: L^T w = z
    #pragma unroll
    for (int i = NSUP - 1; i >= 0; --i) {
        float s = h[i];
        #pragma unroll
        for (int m = i + 1; m < NSUP; ++m) s -= Ls[m * NSUP + i] * h[m];
        h[i] = s * rL[i];
    }
    // ht[i] = sum_{m>=i} R[m][i] * w[m]; exact hi/lo bf16 split
    #pragma unroll
    for (int i = 0; i < NSUP; ++i) {
        float s = 0.f;
        #pragma unroll
        for (int m = i; m < NSUP; ++m) s += Rs[m * NSUP + i] * h[m];
        ushort hh = bf_hi(s);
        float  rr = s - us2f(hh);
        Hth[(cls * NSUP + i) * D + col] = hh;
        Htl[(cls * NSUP + i) * D + col] = bf_hi(rr);
    }
}

// ---- Kernel 2: Z = X @ Htilde^T (3-pass hi/lo bf16 MFMA); S = sum z^2;
// ---- fused min-max epilogue via device-scope ticket (last of 8 cg blocks).
// grid (8 class-groups, 64 batch-pairs), 256 threads = 4 waves (2M x 2N)
__global__ __launch_bounds__(256, 2) void k_main(const float* __restrict__ x,
                                                 const ushort* __restrict__ Hth,
                                                 const ushort* __restrict__ Htl,
                                                 float* __restrict__ S,
                                                 int* __restrict__ ticket,
                                                 float* __restrict__ out) {
    const int cg = blockIdx.x, bp = blockIdx.y;
    const int t = threadIdx.x, lane = t & 63, wid = t >> 6;
    const int wm = wid >> 1, wn = wid & 1;

    // fragment-linear LDS: frag f, lane l -> 16B at [f*512 + l*8] (ushort units)
    __shared__ __align__(16) ushort XH[2][MFRAG * 512];
    __shared__ __align__(16) ushort XL[2][MFRAG * 512];
    __shared__ __align__(16) ushort HH[2][NFRAG * 512];
    __shared__ __align__(16) ushort HL[2][NFRAG * 512];
    __shared__ float colsum[2][COLS];
    __shared__ int lastflag;

    v4f acc[2][5];
    #pragma unroll
    for (int a = 0; a < 2; ++a)
        #pragma unroll
        for (int b = 0; b < 5; ++b) acc[a][b] = (v4f){0.f, 0.f, 0.f, 0.f};

    auto stageX = [&](int buf, int kt) {
        #pragma unroll
        for (int s2 = 0; s2 < 2; ++s2) {
            int g = t + 256 * s2;           // 0..511
            int p = g >> 3;                 // padded row 0..63
            int k0 = (g & 7) << 2;          // 0,4,...,28
            float4 v = make_float4(0.f, 0.f, 0.f, 0.f);
            int r = p & 31;
            if (r < RES)
                v = *(const float4*)&x[(((bp << 1) + (p >> 5)) * RES + r) * D + kt + k0];
            ushort4 hu, lu;
            {
                ushort h; float rr;
                h = bf_hi(v.x); rr = v.x - us2f(h); hu.x = h; lu.x = bf_hi(rr);
                h = bf_hi(v.y); rr = v.y - us2f(h); hu.y = h; lu.y = bf_hi(rr);
                h = bf_hi(v.z); rr = v.z - us2f(h); hu.z = h; lu.z = bf_hi(rr);
                h = bf_hi(v.w); rr = v.w - us2f(h); hu.w = h; lu.w = bf_hi(rr);
            }
            int m = p >> 4, i = p & 15, q = k0 >> 3, off = (k0 & 7);
            int base = m * 512 + (q * 16 + i) * 8 + off;
            *(ushort4*)&XH[buf][base] = hu;
            *(ushort4*)&XL[buf][base] = lu;
        }
    };

    auto stageH = [&](int buf, int kt) {
        #pragma unroll
        for (int j = 0; j < 5; ++j) {
            int cid = wid * 5 + j;                       // 0..19
            int n = (cid < 10) ? cid : cid - 10;
            const ushort* src = (cid < 10) ? Hth : Htl;
            ushort* dst = (cid < 10) ? &HH[buf][n * 512] : &HL[buf][n * 512];
            int row = cg * COLS + n * 16 + (lane & 15);
            const ushort* gp = &src[row * D + kt + ((lane >> 4) << 3)];
            __builtin_amdgcn_global_load_lds(
                (const __attribute__((address_space(1))) void*)gp,
                (__attribute__((address_space(3))) void*)dst, 16, 0, 0);
        }
    };

    auto compute = [&](int buf) {
        v8bf ah[2], al[2];
        #pragma unroll
        for (int mf = 0; mf < 2; ++mf) {
            int f = wm * 2 + mf;
            ah[mf] = *(const v8bf*)&XH[buf][f * 512 + lane * 8];
            al[mf] = *(const v8bf*)&XL[buf][f * 512 + lane * 8];
        }
        #pragma unroll
        for (int nf = 0; nf < 5; ++nf) {
            int f = wn * 5 + nf;
            v8bf bh = *(const v8bf*)&HH[buf][f * 512 + lane * 8];
            v8bf bl = *(const v8bf*)&HL[buf][f * 512 + lane * 8];
            #pragma unroll
            for (int mf = 0; mf < 2; ++mf) {
                // 3-pass: drop al*bl (<= 2^-18 relative)
                acc[mf][nf] = __builtin_amdgcn_mfma_f32_16x16x32_bf16(ah[mf], bh, acc[mf][nf], 0, 0, 0);
                acc[mf][nf] = __builtin_amdgcn_mfma_f32_16x16x32_bf16(ah[mf], bl, acc[mf][nf], 0, 0, 0);
                acc[mf][nf] = __builtin_amdgcn_mfma_f32_16x16x32_bf16(al[mf], bh, acc[mf][nf], 0, 0, 0);
            }
        }
    };

    stageX(0, 0);
    stageH(0, 0);
    __syncthreads();
    for (int step = 0; step < NKT; ++step) {
        int cur = step & 1;
        if (step + 1 < NKT) {
            stageH(cur ^ 1, (step + 1) * KT);
            stageX(cur ^ 1, (step + 1) * KT);
        }
        compute(cur);
        __syncthreads();
    }

    // z^2 column sums; C-frag: col = lane&15, row = 4*(lane>>4)+j
    #pragma unroll
    for (int nf = 0; nf < 5; ++nf) {
        float part = 0.f;
        #pragma unroll
        for (int mf = 0; mf < 2; ++mf)
            #pragma unroll
            for (int j = 0; j < 4; ++j) part += acc[mf][nf][j] * acc[mf][nf][j];
        part += __shfl_xor(part, 16);
        part += __shfl_xor(part, 32);
        if ((lane >> 4) == 0) colsum[wm][wn * 80 + nf * 16 + lane] = part;
    }
    __syncthreads();
    if (t < 16) {
        int b = t >> 3, c = t & 7;
        float s = 0.f;
        #pragma unroll
        for (int i = 0; i < NSUP; ++i) s += colsum[b][c * 20 + i];
        __hip_atomic_store(&S[((bp << 1) + b) * NC + cg * CPB + c], s,
                           __ATOMIC_RELAXED, __HIP_MEMORY_SCOPE_AGENT);
    }
    __syncthreads();
    __threadfence();                      // flush S to device coherence point
    if (t == 0) {
        int old = atomicAdd(&ticket[bp], 1);   // device-scope RMW
        lastflag = (old == CPB - 1);
    }
    __syncthreads();
    if (lastflag && t < 128) {            // last of 8 blocks: min-max 2 rows
        int row = (bp << 1) + (t >> 6);
        int c   = t & 63;
        float s = __hip_atomic_load(&S[row * NC + c],
                                    __ATOMIC_RELAXED, __HIP_MEMORY_SCOPE_AGENT);
        float mn = s, mx = s;
        #pragma unroll
        for (int off = 32; off > 0; off >>= 1) {
            mn = fminf(mn, __shfl_xor(mn, off, 64));
            mx = fmaxf(mx, __shfl_xor(mx, off, 64));
        }
        out[row * NC + c] = (s - mn) / (mx - mn);
    }
}

extern "C" void kernel_launch(void* const* d_in, const int* in_sizes, int n_in,
                              void* d_out, int out_size, void* d_ws, size_t ws_size,
                              hipStream_t stream) {
    const float* x    = (const float*)d_in[0];
    const float* high = (const float*)d_in[1];
    float* out = (float*)d_out;

    ushort* Hth    = (ushort*)d_ws;                    // 64*20*512 u16 = 1.31 MB
    ushort* Htl    = Hth + NC * NSUP * D;              // 1.31 MB
    float*  S      = (float*)(Htl + NC * NSUP * D);    // 32 KB
    int*    ticket = (int*)(S + BB * NC);              // 64 ints (zeroed by k_prep)

    k_prep <<<dim3(NC, 2), 256, 0, stream>>>(high, Hth, Htl, ticket);
    k_main <<<dim3(CPB, BB / 2), 256, 0, stream>>>(x, Hth, Htl, S, ticket, out);
}

// Round 11
// 124.511 us; speedup vs baseline: 1.0841x; 1.0841x over previous
//
#include <hip/hip_runtime.h>

typedef __bf16 v8bf __attribute__((ext_vector_type(8)));
typedef float  v4f  __attribute__((ext_vector_type(4)));

#define D     512
#define NSUP  20
#define NC    64
#define RES   25
#define BB    128
#define LAM   (20.0f/512.0f)
#define KT    32
#define NKT   (D/KT)     // 16
#define CPB   8
#define COLS  160        // CPB*NSUP

__device__ __forceinline__ ushort bf_hi(float v) {
    uint32_t b = __float_as_uint(v);
    return (ushort)((b + 0x7FFF + ((b >> 16) & 1)) >> 16);   // RNE
}
__device__ __forceinline__ float us2f(ushort u) {
    return __uint_as_float(((uint32_t)u) << 16);
}

// ---- Kernel 1 (fused): Gram + dual register-Cholesky + panel solves --------
//  B = G+lam I = L L^T ; C2 = G+2lam I = R R^T ; W = B^{-1}H ; Htilde = R^T W.
__global__ __launch_bounds__(256) void k_prep(const float* __restrict__ high,
                                              ushort* __restrict__ Hth,
                                              ushort* __restrict__ Htl) {
    const int cls  = blockIdx.x;
    const int half = blockIdx.y;
    const int t    = threadIdx.x;
    __shared__ float Hc[NSUP * 516];
    __shared__ float Gs[NSUP * NSUP];
    __shared__ float Ls[400], Rs[400], rL[NSUP];

    for (int i = t; i < NSUP * (D / 4); i += 256) {
        int r = i >> 7, c4 = (i & 127) << 2;
        *(float4*)&Hc[r * 516 + c4] = *(const float4*)&high[(cls * NSUP + r) * D + c4];
    }
    __syncthreads();

    // Gram — symmetric half only
    for (int e = t; e < NSUP * NSUP; e += 256) {
        int i = e / NSUP, j = e % NSUP;
        if (i <= j) {
            float s = 0.f;
            for (int k = 0; k < D; k += 4) {
                float4 a = *(float4*)&Hc[i * 516 + k];
                float4 b = *(float4*)&Hc[j * 516 + k];
                s += a.x * b.x + a.y * b.y + a.z * b.z + a.w * b.w;
            }
            Gs[i * NSUP + j] = s;
            Gs[j * NSUP + i] = s;
        }
    }
    __syncthreads();

    // dual in-register Cholesky on wave 0 (lanes 0-19: B, 32-51: C2)
    if (t < 64) {
        const int c  = t & 31;
        const int gp = t >> 5;
        const float dlam = gp ? 2.0f * LAM : LAM;
        float m[NSUP];
        if (c < NSUP) {
            #pragma unroll
            for (int i = 0; i < NSUP; ++i) m[i] = Gs[i * NSUP + c];
            #pragma unroll
            for (int i = 0; i < NSUP; ++i) if (i == c) m[i] += dlam;
        }
        #pragma unroll
        for (int k = 0; k < NSUP; ++k) {
            float piv = __shfl(m[k], k, 32);     // M[k][k] from lane k
            float sq  = sqrtf(piv);
            float rsq = 1.0f / sq;
            float lck = m[k] * rsq;              // L[c][k] via symmetry (c>k)
            if (c == k) {
                m[k] = sq;
                #pragma unroll
                for (int i = k + 1; i < NSUP; ++i) m[i] *= rsq;
            }
            #pragma unroll
            for (int i = k + 1; i < NSUP; ++i) {
                float lik = __shfl(m[i], k, 32); // L[i][k] (post-scale)
                if (c > k) m[i] -= lik * lck;
            }
        }
        if (c < NSUP) {
            float* Lout = gp ? Rs : Ls;
            #pragma unroll
            for (int i = 0; i < NSUP; ++i) if (i >= c) Lout[i * NSUP + c] = m[i];
            if (!gp) rL[c] = 1.0f / m[c];
        }
    }
    __syncthreads();

    // panel solves for this block's 256 columns (H from LDS)
    const int col = half * 256 + t;
    float h[NSUP];
    #pragma unroll
    for (int m = 0; m < NSUP; ++m) h[m] = Hc[m * 516 + col];
    #pragma unroll
    for (int i = 0; i < NSUP; ++i) {            // forward: L z = h
        float s = h[i];
        #pragma unroll
        for (int m = 0; m < i; ++m) s -= Ls[i * NSUP + m] * h[m];
        h[i] = s * rL[i];
    }
    #pragma unroll
    for (int i = NSUP - 1; i >= 0; --i) {       // backward: L^T w = z
        float s = h[i];
        #pragma unroll
        for (int m = i + 1; m < NSUP; ++m) s -= Ls[m * NSUP + i] * h[m];
        h[i] = s * rL[i];
    }
    #pragma unroll
    for (int i = 0; i < NSUP; ++i) {            // ht = R^T w; hi/lo split
        float s = 0.f;
        #pragma unroll
        for (int m = i; m < NSUP; ++m) s += Rs[m * NSUP + i] * h[m];
        ushort hh = bf_hi(s);
        float  rr = s - us2f(hh);
        Hth[(cls * NSUP + i) * D + col] = hh;
        Htl[(cls * NSUP + i) * D + col] = bf_hi(rr);
    }
}

// ---- Kernel 2: Z = X @ Htilde^T, all-register, ZERO barriers in K loop -----
// grid (8 class-groups, 64 batch-pairs), 256 threads = 4 waves (2M x 2N).
// Each wave: A-frags (X hi/lo, split in-regs) + B-frags (Hth/Htl) straight
// from global to VGPRs. 3-pass MFMA. LDS only for the tiny epilogue.
__global__ __launch_bounds__(256, 4) void k_main(const float* __restrict__ x,
                                                 const ushort* __restrict__ Hth,
                                                 const ushort* __restrict__ Htl,
                                                 float* __restrict__ S) {
    const int cg = blockIdx.x, bp = blockIdx.y;
    const int t = threadIdx.x, lane = t & 63, wid = t >> 6;
    const int wm = wid >> 1, wn = wid & 1;
    const int r16 = lane & 15, q = lane >> 4;        // frag row, k-quad

    __shared__ float colsum[2][COLS];

    v4f acc[2][5];
    #pragma unroll
    for (int a = 0; a < 2; ++a)
        #pragma unroll
        for (int b = 0; b < 5; ++b) acc[a][b] = (v4f){0.f, 0.f, 0.f, 0.f};

    // per-lane A geometry (frag f = wm*2+mf): tile row tr = f*16 + r16
    bool  avalid[2];
    const float* aptr[2];
    #pragma unroll
    for (int mf = 0; mf < 2; ++mf) {
        int f  = wm * 2 + mf;
        int tr = f * 16 + r16;
        int batch = (bp << 1) + (tr >> 5);
        int rb = tr & 31;
        avalid[mf] = rb < RES;
        aptr[mf] = &x[(batch * RES + (avalid[mf] ? rb : 0)) * D + (q << 3)];
    }
    // per-lane B pointers (frag f = wn*5+nf)
    const ushort* bptrh[5];
    const ushort* bptrl[5];
    #pragma unroll
    for (int nf = 0; nf < 5; ++nf) {
        int f   = wn * 5 + nf;
        int row = cg * COLS + f * 16 + r16;
        bptrh[nf] = &Hth[row * D + (q << 3)];
        bptrl[nf] = &Htl[row * D + (q << 3)];
    }

    for (int kt = 0; kt < D; kt += KT) {
        // A: 8 f32 per lane -> exact hi/lo bf16 split in registers
        v8bf ah[2], al[2];
        #pragma unroll
        for (int mf = 0; mf < 2; ++mf) {
            float4 v0 = make_float4(0.f, 0.f, 0.f, 0.f), v1 = v0;
            if (avalid[mf]) {
                v0 = *(const float4*)(aptr[mf] + kt);
                v1 = *(const float4*)(aptr[mf] + kt + 4);
            }
            float vv[8] = {v0.x, v0.y, v0.z, v0.w, v1.x, v1.y, v1.z, v1.w};
            #pragma unroll
            for (int e = 0; e < 8; ++e) {
                ushort h = bf_hi(vv[e]);
                float  r = vv[e] - us2f(h);
                ((ushort*)&ah[mf])[e] = h;
                ((ushort*)&al[mf])[e] = bf_hi(r);
            }
        }
        #pragma unroll
        for (int nf = 0; nf < 5; ++nf) {
            v8bf bh = *(const v8bf*)(bptrh[nf] + kt);
            v8bf bl = *(const v8bf*)(bptrl[nf] + kt);
            #pragma unroll
            for (int mf = 0; mf < 2; ++mf) {
                // 3-pass: drop al*bl (<= 2^-18 relative)
                acc[mf][nf] = __builtin_amdgcn_mfma_f32_16x16x32_bf16(ah[mf], bh, acc[mf][nf], 0, 0, 0);
                acc[mf][nf] = __builtin_amdgcn_mfma_f32_16x16x32_bf16(ah[mf], bl, acc[mf][nf], 0, 0, 0);
                acc[mf][nf] = __builtin_amdgcn_mfma_f32_16x16x32_bf16(al[mf], bh, acc[mf][nf], 0, 0, 0);
            }
        }
    }

    // z^2 column sums; C-frag: col = lane&15, row = 4*(lane>>4)+j
    #pragma unroll
    for (int nf = 0; nf < 5; ++nf) {
        float part = 0.f;
        #pragma unroll
        for (int mf = 0; mf < 2; ++mf)
            #pragma unroll
            for (int j = 0; j < 4; ++j) part += acc[mf][nf][j] * acc[mf][nf][j];
        part += __shfl_xor(part, 16);
        part += __shfl_xor(part, 32);
        if (q == 0) colsum[wm][wn * 80 + nf * 16 + r16] = part;
    }
    __syncthreads();
    if (t < 16) {
        int b = t >> 3, c = t & 7;
        float s = 0.f;
        #pragma unroll
        for (int i = 0; i < NSUP; ++i) s += colsum[b][c * 20 + i];
        S[((bp << 1) + b) * NC + cg * CPB + c] = s;
    }
}

// ---- Kernel 3: per-row min-max ----
__global__ __launch_bounds__(64) void k_minmax(const float* __restrict__ S,
                                               float* __restrict__ out) {
    const int b    = blockIdx.x;
    const int lane = threadIdx.x;
    float s  = S[b * NC + lane];
    float mn = s, mx = s;
    #pragma unroll
    for (int off = 32; off > 0; off >>= 1) {
        mn = fminf(mn, __shfl_xor(mn, off, 64));
        mx = fmaxf(mx, __shfl_xor(mx, off, 64));
    }
    out[b * NC + lane] = (s - mn) / (mx - mn);
}

extern "C" void kernel_launch(void* const* d_in, const int* in_sizes, int n_in,
                              void* d_out, int out_size, void* d_ws, size_t ws_size,
                              hipStream_t stream) {
    const float* x    = (const float*)d_in[0];
    const float* high = (const float*)d_in[1];
    float* out = (float*)d_out;

    ushort* Hth = (ushort*)d_ws;                       // 64*20*512 u16 = 1.31 MB
    ushort* Htl = Hth + NC * NSUP * D;                 // 1.31 MB
    float*  S   = (float*)(Htl + NC * NSUP * D);       // 32 KB

    k_prep  <<<dim3(NC, 2), 256, 0, stream>>>(high, Hth, Htl);
    k_main  <<<dim3(CPB, BB / 2), 256, 0, stream>>>(x, Hth, Htl, S);
    k_minmax<<<BB, 64, 0, stream>>>(S, out);
}